// Round 1
// baseline (75.065 us; speedup 1.0000x reference)
//
#include <hip/hip_runtime.h>
#include <math.h>

#define NB   4
#define SEQN 512
#define SEQM 512
#define QS   256   // Q_SIZE == K_SIZE
#define HH   128   // H
#define DV   256   // D_V

// 2*log2(e): pre-scale q,k so exp2(q'+k') == exp(2*(q+k))
static constexpr float kPreScale = 2.8853900817779268f;
static constexpr float kLog2e    = 1.4426950408889634f;

#if __has_builtin(__builtin_amdgcn_exp2f)
__device__ __forceinline__ float fexp2(float x) { return __builtin_amdgcn_exp2f(x); }
#else
__device__ __forceinline__ float fexp2(float x) { return exp2f(x); }
#endif

#if __has_builtin(__builtin_amdgcn_rcpf)
__device__ __forceinline__ float frcp(float x) { return __builtin_amdgcn_rcpf(x); }
#else
__device__ __forceinline__ float frcp(float x) { return 1.0f / x; }
#endif

// out[row][j] = scale * sum_k in[row][k] * W[k][j]
// grid: 2048/8 = 256 blocks, 256 threads. Each block: 8 rows x 128 cols.
__global__ __launch_bounds__(256) void proj_kernel(
    const float* __restrict__ in, const float* __restrict__ W,
    float* __restrict__ out, float scale) {
  __shared__ float in_lds[8][QS];   // 8 KB
  const int t = threadIdx.x;
  const int row0 = blockIdx.x * 8;

  // stage 8 input rows: 2048 floats = 512 float4 by 256 threads
  const float4* src = reinterpret_cast<const float4*>(in + (size_t)row0 * QS);
  float4* dst = reinterpret_cast<float4*>(&in_lds[0][0]);
  dst[t] = src[t];
  dst[t + 256] = src[t + 256];
  __syncthreads();

  const int j  = t & 127;         // output column
  const int r0 = (t >> 7) * 4;    // 4 rows per thread-half
  float a0 = 0.f, a1 = 0.f, a2 = 0.f, a3 = 0.f;
  for (int k0 = 0; k0 < QS; k0 += 4) {
    // W[k][j]: coalesced across j
    const float w0 = W[(k0 + 0) * HH + j];
    const float w1 = W[(k0 + 1) * HH + j];
    const float w2 = W[(k0 + 2) * HH + j];
    const float w3 = W[(k0 + 3) * HH + j];
    // wave-uniform LDS reads -> broadcast, no conflicts
    const float4 x0 = *reinterpret_cast<const float4*>(&in_lds[r0 + 0][k0]);
    const float4 x1 = *reinterpret_cast<const float4*>(&in_lds[r0 + 1][k0]);
    const float4 x2 = *reinterpret_cast<const float4*>(&in_lds[r0 + 2][k0]);
    const float4 x3 = *reinterpret_cast<const float4*>(&in_lds[r0 + 3][k0]);
    a0 = fmaf(x0.x, w0, fmaf(x0.y, w1, fmaf(x0.z, w2, fmaf(x0.w, w3, a0))));
    a1 = fmaf(x1.x, w0, fmaf(x1.y, w1, fmaf(x1.z, w2, fmaf(x1.w, w3, a1))));
    a2 = fmaf(x2.x, w0, fmaf(x2.y, w1, fmaf(x2.z, w2, fmaf(x2.w, w3, a2))));
    a3 = fmaf(x3.x, w0, fmaf(x3.y, w1, fmaf(x3.z, w2, fmaf(x3.w, w3, a3))));
  }
  out[(size_t)(row0 + r0 + 0) * HH + j] = a0 * scale;
  out[(size_t)(row0 + r0 + 1) * HH + j] = a1 * scale;
  out[(size_t)(row0 + r0 + 2) * HH + j] = a2 * scale;
  out[(size_t)(row0 + r0 + 3) * HH + j] = a3 * scale;
}

// Fused scores + softmax + PV.
// grid: NB * (SEQN/TN) = 4*64 = 256 blocks, 256 threads.
// scores[n][m] (up to softmax shift) = -2 * sum_h wv[h] / (exp2(q'[n][h]+k'[m][h]) + 1)
__global__ __launch_bounds__(256) void attn_kernel(
    const float* __restrict__ qp, const float* __restrict__ kp,
    const float* __restrict__ value, const float* __restrict__ wv,
    float* __restrict__ out) {
  constexpr int TN = 8;
  constexpr int HC = 16;
  __shared__ float sc[TN][SEQM];      // 16 KB: scores, then unnormalized p
  __shared__ float rowscale[TN];

  const int t  = threadIdx.x;
  const int b  = blockIdx.x / (SEQN / TN);
  const int n0 = (blockIdx.x % (SEQN / TN)) * TN;

  const float* __restrict__ qb = qp + ((size_t)b * SEQN + n0) * HH;
  const float* __restrict__ kb = kp + (size_t)b * SEQM * HH;

  const int m1 = t;          // this lane's two key rows
  const int m2 = t + 256;

  float z0[TN], z1[TN];
#pragma unroll
  for (int n = 0; n < TN; ++n) { z0[n] = 0.f; z1[n] = 0.f; }

  for (int h0 = 0; h0 < HH; h0 += HC) {
    float ka[HC], kc[HC], wl[HC];
#pragma unroll
    for (int u = 0; u < HC / 4; ++u) {
      const float4 f1 = *reinterpret_cast<const float4*>(kb + (size_t)m1 * HH + h0 + 4 * u);
      const float4 f2 = *reinterpret_cast<const float4*>(kb + (size_t)m2 * HH + h0 + 4 * u);
      const float4 w4 = *reinterpret_cast<const float4*>(wv + h0 + 4 * u);
      ka[4*u+0] = f1.x; ka[4*u+1] = f1.y; ka[4*u+2] = f1.z; ka[4*u+3] = f1.w;
      kc[4*u+0] = f2.x; kc[4*u+1] = f2.y; kc[4*u+2] = f2.z; kc[4*u+3] = f2.w;
      wl[4*u+0] = w4.x; wl[4*u+1] = w4.y; wl[4*u+2] = w4.z; wl[4*u+3] = w4.w;
    }
#pragma unroll
    for (int n = 0; n < TN; ++n) {
      float qv[HC];
#pragma unroll
      for (int u = 0; u < HC / 4; ++u) {
        // thread-invariant address -> scalar (s_load) path
        const float4 q4 = *reinterpret_cast<const float4*>(qb + n * HH + h0 + 4 * u);
        qv[4*u+0] = q4.x; qv[4*u+1] = q4.y; qv[4*u+2] = q4.z; qv[4*u+3] = q4.w;
      }
#pragma unroll
      for (int jj = 0; jj < HC; ++jj) {
        const float x1 = qv[jj] + ka[jj];
        const float x2 = qv[jj] + kc[jj];
        const float r1 = frcp(fexp2(x1) + 1.0f);
        const float r2 = frcp(fexp2(x2) + 1.0f);
        z0[n] = fmaf(wl[jj], r1, z0[n]);
        z1[n] = fmaf(wl[jj], r2, z1[n]);
      }
    }
  }

#pragma unroll
  for (int n = 0; n < TN; ++n) {
    sc[n][m1] = -2.0f * z0[n];
    sc[n][m2] = -2.0f * z1[n];
  }
  __syncthreads();

  // softmax over m: wave w owns rows 2w, 2w+1
  const int wave = t >> 6;
  const int lane = t & 63;
#pragma unroll
  for (int r = 0; r < 2; ++r) {
    const int n = wave * 2 + r;
    float v[8];
    float mx = -INFINITY;
#pragma unroll
    for (int i = 0; i < 8; ++i) {
      v[i] = sc[n][lane + 64 * i];
      mx = fmaxf(mx, v[i]);
    }
#pragma unroll
    for (int off = 32; off > 0; off >>= 1) mx = fmaxf(mx, __shfl_xor(mx, off));
    float sum = 0.f;
#pragma unroll
    for (int i = 0; i < 8; ++i) {
      const float p = fexp2((v[i] - mx) * kLog2e);
      sum += p;
      sc[n][lane + 64 * i] = p;   // unnormalized
    }
#pragma unroll
    for (int off = 32; off > 0; off >>= 1) sum += __shfl_xor(sum, off);
    if (lane == 0) rowscale[n] = 1.0f / sum;
  }
  __syncthreads();

  // PV: out[n][d] = rowscale[n] * sum_m p[n][m] * value[b][m][d]; d = t
  const float* __restrict__ vb = value + (size_t)b * SEQM * DV;
  const int d = t;
  float o[TN];
#pragma unroll
  for (int n = 0; n < TN; ++n) o[n] = 0.f;
  for (int m0 = 0; m0 < SEQM; m0 += 4) {
    const float v0 = vb[(size_t)(m0 + 0) * DV + d];
    const float v1 = vb[(size_t)(m0 + 1) * DV + d];
    const float v2 = vb[(size_t)(m0 + 2) * DV + d];
    const float v3 = vb[(size_t)(m0 + 3) * DV + d];
#pragma unroll
    for (int n = 0; n < TN; ++n) {
      const float4 p4 = *reinterpret_cast<const float4*>(&sc[n][m0]);
      o[n] = fmaf(p4.x, v0, fmaf(p4.y, v1, fmaf(p4.z, v2, fmaf(p4.w, v3, o[n]))));
    }
  }
  const size_t ob = ((size_t)b * SEQN + n0) * DV + (size_t)d;
#pragma unroll
  for (int n = 0; n < TN; ++n) out[ob + (size_t)n * DV] = o[n] * rowscale[n];
}

extern "C" void kernel_launch(void* const* d_in, const int* in_sizes, int n_in,
                              void* d_out, int out_size, void* d_ws, size_t ws_size,
                              hipStream_t stream) {
  const float* query = (const float*)d_in[0];   // (4,512,256)
  const float* key   = (const float*)d_in[1];   // (4,512,256)
  const float* value = (const float*)d_in[2];   // (4,512,256)
  const float* W_q   = (const float*)d_in[3];   // (256,128)
  const float* W_k   = (const float*)d_in[4];   // (256,128)
  const float* W_v   = (const float*)d_in[5];   // (128,)
  float* out = (float*)d_out;                   // (4,512,256) f32

  float* qp = (float*)d_ws;                     // (4*512,128) pre-scaled q
  float* kp = qp + (size_t)NB * SEQN * HH;      // (4*512,128) pre-scaled k

  proj_kernel<<<(NB * SEQN) / 8, 256, 0, stream>>>(query, W_q, qp, kPreScale);
  proj_kernel<<<(NB * SEQM) / 8, 256, 0, stream>>>(key,   W_k, kp, kPreScale);
  attn_kernel<<<NB * (SEQN / 8), 256, 0, stream>>>(qp, kp, value, W_v, out);
}

// Round 2
// 71.017 us; speedup vs baseline: 1.0570x; 1.0570x over previous
//
#include <hip/hip_runtime.h>
#include <math.h>

#define NB   4
#define SEQN 512
#define SEQM 512
#define QS   256   // Q_SIZE == K_SIZE
#define HH   128   // H
#define DV   256   // D_V

// 2*log2(e): pre-scale q,k so exp2(q'+k') == exp(2*(q+k))
static constexpr float kPreScale = 2.8853900817779268f;
static constexpr float kLog2e    = 1.4426950408889634f;

#if __has_builtin(__builtin_amdgcn_exp2f)
__device__ __forceinline__ float fexp2(float x) { return __builtin_amdgcn_exp2f(x); }
#else
__device__ __forceinline__ float fexp2(float x) { return exp2f(x); }
#endif

#if __has_builtin(__builtin_amdgcn_rcpf)
__device__ __forceinline__ float frcp(float x) { return __builtin_amdgcn_rcpf(x); }
#else
__device__ __forceinline__ float frcp(float x) { return 1.0f / x; }
#endif

// out[row][j] = scale * sum_k in[row][k] * W[k][j]
// grid: 2048/8 = 256 blocks, 256 threads. Each block: 8 rows x 128 cols.
__global__ __launch_bounds__(256) void proj_kernel(
    const float* __restrict__ in, const float* __restrict__ W,
    float* __restrict__ out, float scale) {
  __shared__ float in_lds[8][QS];   // 8 KB
  const int t = threadIdx.x;
  const int row0 = blockIdx.x * 8;

  const float4* src = reinterpret_cast<const float4*>(in + (size_t)row0 * QS);
  float4* dst = reinterpret_cast<float4*>(&in_lds[0][0]);
  dst[t] = src[t];
  dst[t + 256] = src[t + 256];
  __syncthreads();

  const int j  = t & 127;         // output column
  const int r0 = (t >> 7) * 4;    // 4 rows per thread-half
  float a0 = 0.f, a1 = 0.f, a2 = 0.f, a3 = 0.f;
  for (int k0 = 0; k0 < QS; k0 += 4) {
    const float w0 = W[(k0 + 0) * HH + j];
    const float w1 = W[(k0 + 1) * HH + j];
    const float w2 = W[(k0 + 2) * HH + j];
    const float w3 = W[(k0 + 3) * HH + j];
    const float4 x0 = *reinterpret_cast<const float4*>(&in_lds[r0 + 0][k0]);
    const float4 x1 = *reinterpret_cast<const float4*>(&in_lds[r0 + 1][k0]);
    const float4 x2 = *reinterpret_cast<const float4*>(&in_lds[r0 + 2][k0]);
    const float4 x3 = *reinterpret_cast<const float4*>(&in_lds[r0 + 3][k0]);
    a0 = fmaf(x0.x, w0, fmaf(x0.y, w1, fmaf(x0.z, w2, fmaf(x0.w, w3, a0))));
    a1 = fmaf(x1.x, w0, fmaf(x1.y, w1, fmaf(x1.z, w2, fmaf(x1.w, w3, a1))));
    a2 = fmaf(x2.x, w0, fmaf(x2.y, w1, fmaf(x2.z, w2, fmaf(x2.w, w3, a2))));
    a3 = fmaf(x3.x, w0, fmaf(x3.y, w1, fmaf(x3.z, w2, fmaf(x3.w, w3, a3))));
  }
  out[(size_t)(row0 + r0 + 0) * HH + j] = a0 * scale;
  out[(size_t)(row0 + r0 + 1) * HH + j] = a1 * scale;
  out[(size_t)(row0 + r0 + 2) * HH + j] = a2 * scale;
  out[(size_t)(row0 + r0 + 3) * HH + j] = a3 * scale;
}

// Fused scores + softmax + PV.
// grid: NB * (SEQN/TN) = 4*128 = 512 blocks, 512 threads (8 waves).
// Each thread owns ONE key row m = tid; TN=4 query rows per block.
__global__ __launch_bounds__(512) void attn_kernel(
    const float* __restrict__ qp, const float* __restrict__ kp,
    const float* __restrict__ value, const float* __restrict__ wv,
    float* __restrict__ out) {
  constexpr int TN = 4;
  constexpr int HC = 16;
  __shared__ float sc[TN][SEQM];      // 8 KB: scores, then unnormalized p
  __shared__ float pv[TN][DV];        // 4 KB: PV half-combine
  __shared__ float wmax[8];
  __shared__ float wsum[8];

  const int t  = threadIdx.x;         // 0..511
  const int b  = blockIdx.x / (SEQN / TN);
  const int n0 = (blockIdx.x % (SEQN / TN)) * TN;

  const float* __restrict__ qb = qp + ((size_t)b * SEQN + n0) * HH;
  const float* __restrict__ kb = kp + (size_t)b * SEQM * HH + (size_t)t * HH;

  float z[TN];
#pragma unroll
  for (int n = 0; n < TN; ++n) z[n] = 0.f;

  for (int h0 = 0; h0 < HH; h0 += HC) {
    float ka[HC], wl[HC];
#pragma unroll
    for (int u = 0; u < HC / 4; ++u) {
      const float4 f1 = *reinterpret_cast<const float4*>(kb + h0 + 4 * u);
      const float4 w4 = *reinterpret_cast<const float4*>(wv + h0 + 4 * u);  // uniform -> SGPR
      ka[4*u+0] = f1.x; ka[4*u+1] = f1.y; ka[4*u+2] = f1.z; ka[4*u+3] = f1.w;
      wl[4*u+0] = w4.x; wl[4*u+1] = w4.y; wl[4*u+2] = w4.z; wl[4*u+3] = w4.w;
    }
#pragma unroll
    for (int n = 0; n < TN; ++n) {
      float qv[HC];
#pragma unroll
      for (int u = 0; u < HC / 4; ++u) {
        const float4 q4 = *reinterpret_cast<const float4*>(qb + n * HH + h0 + 4 * u);  // uniform
        qv[4*u+0] = q4.x; qv[4*u+1] = q4.y; qv[4*u+2] = q4.z; qv[4*u+3] = q4.w;
      }
#pragma unroll
      for (int jj = 0; jj < HC; ++jj) {
        const float r1 = frcp(fexp2(qv[jj] + ka[jj]) + 1.0f);
        z[n] = fmaf(wl[jj], r1, z[n]);
      }
    }
  }

#pragma unroll
  for (int n = 0; n < TN; ++n) sc[n][t] = -2.0f * z[n];
  __syncthreads();

  // softmax over m: 8 waves, 4 rows -> 2 waves per row (each handles 256 elems)
  const int wave = t >> 6;
  const int lane = t & 63;
  const int row  = wave & 3;
  const int half = wave >> 2;
  float v[4];
  float mx = -INFINITY;
#pragma unroll
  for (int i = 0; i < 4; ++i) {
    v[i] = sc[row][half * 256 + lane + 64 * i];
    mx = fmaxf(mx, v[i]);
  }
#pragma unroll
  for (int off = 32; off > 0; off >>= 1) mx = fmaxf(mx, __shfl_xor(mx, off));
  if (lane == 0) wmax[wave] = mx;
  __syncthreads();
  mx = fmaxf(wmax[row], wmax[row + 4]);
  float sum = 0.f;
#pragma unroll
  for (int i = 0; i < 4; ++i) {
    const float p = fexp2((v[i] - mx) * kLog2e);
    sum += p;
    sc[row][half * 256 + lane + 64 * i] = p;   // unnormalized
  }
#pragma unroll
  for (int off = 32; off > 0; off >>= 1) sum += __shfl_xor(sum, off);
  if (lane == 0) wsum[wave] = sum;
  __syncthreads();

  // PV: thread half owns 256 m's; d = t & 255; combine halves via LDS
  const float* __restrict__ vb = value + (size_t)b * SEQM * DV;
  const int d  = t & 255;
  const int mh = (t >> 8) * 256;
  float o[TN];
#pragma unroll
  for (int n = 0; n < TN; ++n) o[n] = 0.f;
  for (int m0 = mh; m0 < mh + 256; m0 += 4) {
    const float v0 = vb[(size_t)(m0 + 0) * DV + d];
    const float v1 = vb[(size_t)(m0 + 1) * DV + d];
    const float v2 = vb[(size_t)(m0 + 2) * DV + d];
    const float v3 = vb[(size_t)(m0 + 3) * DV + d];
#pragma unroll
    for (int n = 0; n < TN; ++n) {
      const float4 p4 = *reinterpret_cast<const float4*>(&sc[n][m0]);  // broadcast
      o[n] = fmaf(p4.x, v0, fmaf(p4.y, v1, fmaf(p4.z, v2, fmaf(p4.w, v3, o[n]))));
    }
  }
  if (t >= 256) {
#pragma unroll
    for (int n = 0; n < TN; ++n) pv[n][d] = o[n];
  }
  __syncthreads();
  if (t < 256) {
    const size_t ob = ((size_t)b * SEQN + n0) * DV + (size_t)d;
#pragma unroll
    for (int n = 0; n < TN; ++n) {
      const float scale = 1.0f / (wsum[n] + wsum[n + 4]);
      out[ob + (size_t)n * DV] = (o[n] + pv[n][d]) * scale;
    }
  }
}

extern "C" void kernel_launch(void* const* d_in, const int* in_sizes, int n_in,
                              void* d_out, int out_size, void* d_ws, size_t ws_size,
                              hipStream_t stream) {
  const float* query = (const float*)d_in[0];   // (4,512,256)
  const float* key   = (const float*)d_in[1];   // (4,512,256)
  const float* value = (const float*)d_in[2];   // (4,512,256)
  const float* W_q   = (const float*)d_in[3];   // (256,128)
  const float* W_k   = (const float*)d_in[4];   // (256,128)
  const float* W_v   = (const float*)d_in[5];   // (128,)
  float* out = (float*)d_out;                   // (4,512,256) f32

  float* qp = (float*)d_ws;                     // (4*512,128) pre-scaled q
  float* kp = qp + (size_t)NB * SEQN * HH;      // (4*512,128) pre-scaled k

  proj_kernel<<<(NB * SEQN) / 8, 256, 0, stream>>>(query, W_q, qp, kPreScale);
  proj_kernel<<<(NB * SEQM) / 8, 256, 0, stream>>>(key,   W_k, kp, kPreScale);
  attn_kernel<<<NB * (SEQN / 4), 512, 0, stream>>>(qp, kp, value, W_v, out);
}

// Round 3
// 64.646 us; speedup vs baseline: 1.1612x; 1.0986x over previous
//
#include <hip/hip_runtime.h>
#include <math.h>

#define NB   4
#define SEQN 512
#define SEQM 512
#define QS   256   // Q_SIZE == K_SIZE
#define HH   128   // H
#define DV   256   // D_V

// 2*log2(e): pre-scale q,k so exp2(q'+k') == exp(2*(q+k))
static constexpr float kPreScale = 2.8853900817779268f;
static constexpr float kLog2e    = 1.4426950408889634f;

#if __has_builtin(__builtin_amdgcn_exp2f)
__device__ __forceinline__ float fexp2(float x) { return __builtin_amdgcn_exp2f(x); }
#else
__device__ __forceinline__ float fexp2(float x) { return exp2f(x); }
#endif

#if __has_builtin(__builtin_amdgcn_rcpf)
__device__ __forceinline__ float frcp(float x) { return __builtin_amdgcn_rcpf(x); }
#else
__device__ __forceinline__ float frcp(float x) { return 1.0f / x; }
#endif

// Fused q/k projection. grid: 2 * (2048/8) = 512 blocks, 256 threads.
// Block handles 8 rows x 128 cols of either query@W_q or key@W_k (scaled).
__global__ __launch_bounds__(256) void proj_kernel(
    const float* __restrict__ query, const float* __restrict__ key,
    const float* __restrict__ Wq, const float* __restrict__ Wk,
    float* __restrict__ qp, float* __restrict__ kp) {
  __shared__ float in_lds[8][QS];   // 8 KB
  const int t = threadIdx.x;
  const int half = (NB * SEQN) / 8;            // 256
  const bool isK = blockIdx.x >= half;
  const int rb   = isK ? (blockIdx.x - half) : blockIdx.x;
  const float* __restrict__ in = isK ? key : query;
  const float* __restrict__ W  = isK ? Wk  : Wq;
  float* __restrict__ outp     = isK ? kp  : qp;
  const int row0 = rb * 8;

  const float4* src = reinterpret_cast<const float4*>(in + (size_t)row0 * QS);
  float4* dst = reinterpret_cast<float4*>(&in_lds[0][0]);
  dst[t] = src[t];
  dst[t + 256] = src[t + 256];
  __syncthreads();

  const int j  = t & 127;         // output column
  const int r0 = (t >> 7) * 4;    // 4 rows per thread-half
  float a0 = 0.f, a1 = 0.f, a2 = 0.f, a3 = 0.f;
  for (int k0 = 0; k0 < QS; k0 += 4) {
    const float w0 = W[(k0 + 0) * HH + j];
    const float w1 = W[(k0 + 1) * HH + j];
    const float w2 = W[(k0 + 2) * HH + j];
    const float w3 = W[(k0 + 3) * HH + j];
    const float4 x0 = *reinterpret_cast<const float4*>(&in_lds[r0 + 0][k0]);
    const float4 x1 = *reinterpret_cast<const float4*>(&in_lds[r0 + 1][k0]);
    const float4 x2 = *reinterpret_cast<const float4*>(&in_lds[r0 + 2][k0]);
    const float4 x3 = *reinterpret_cast<const float4*>(&in_lds[r0 + 3][k0]);
    a0 = fmaf(x0.x, w0, fmaf(x0.y, w1, fmaf(x0.z, w2, fmaf(x0.w, w3, a0))));
    a1 = fmaf(x1.x, w0, fmaf(x1.y, w1, fmaf(x1.z, w2, fmaf(x1.w, w3, a1))));
    a2 = fmaf(x2.x, w0, fmaf(x2.y, w1, fmaf(x2.z, w2, fmaf(x2.w, w3, a2))));
    a3 = fmaf(x3.x, w0, fmaf(x3.y, w1, fmaf(x3.z, w2, fmaf(x3.w, w3, a3))));
  }
  outp[(size_t)(row0 + r0 + 0) * HH + j] = a0 * kPreScale;
  outp[(size_t)(row0 + r0 + 1) * HH + j] = a1 * kPreScale;
  outp[(size_t)(row0 + r0 + 2) * HH + j] = a2 * kPreScale;
  outp[(size_t)(row0 + r0 + 3) * HH + j] = a3 * kPreScale;
}

// Scores only. grid = NB * (SEQN/2) * 2 = 2048 blocks, 256 threads, 0 LDS.
// Block: 2 query rows x 256 keys (half). Thread: one key row m.
// sc[b][n][m] = -2 * sum_h wv[h] / (exp2(q'[n][h]+k'[m][h]) + 1)   (unnormalized)
__global__ __launch_bounds__(256, 8) void scores_kernel(
    const float* __restrict__ qp, const float* __restrict__ kp,
    const float* __restrict__ wv, float* __restrict__ sc) {
  const int t = threadIdx.x;
  const int bid = blockIdx.x;
  const int mh = bid & 1;
  const int nt = (bid >> 1) & (SEQN / 2 - 1);   // 0..255
  const int b  = bid >> 9;                      // 0..3
  const int n0 = nt * 2;
  const int m  = mh * 256 + t;

  const float* __restrict__ qb = qp + ((size_t)b * SEQN + n0) * HH;  // uniform
  const float* __restrict__ kb = kp + ((size_t)b * SEQM + m) * HH;

  float z0 = 0.f, z1 = 0.f;
  for (int h0 = 0; h0 < HH; h0 += 16) {
    float ka[16], wl[16], q0[16], q1[16];
#pragma unroll
    for (int u = 0; u < 4; ++u) {
      const float4 f = *reinterpret_cast<const float4*>(kb + h0 + 4 * u);
      const float4 w = *reinterpret_cast<const float4*>(wv + h0 + 4 * u);        // uniform
      const float4 a = *reinterpret_cast<const float4*>(qb + h0 + 4 * u);        // uniform
      const float4 c = *reinterpret_cast<const float4*>(qb + HH + h0 + 4 * u);   // uniform
      ka[4*u+0] = f.x; ka[4*u+1] = f.y; ka[4*u+2] = f.z; ka[4*u+3] = f.w;
      wl[4*u+0] = w.x; wl[4*u+1] = w.y; wl[4*u+2] = w.z; wl[4*u+3] = w.w;
      q0[4*u+0] = a.x; q0[4*u+1] = a.y; q0[4*u+2] = a.z; q0[4*u+3] = a.w;
      q1[4*u+0] = c.x; q1[4*u+1] = c.y; q1[4*u+2] = c.z; q1[4*u+3] = c.w;
    }
#pragma unroll
    for (int jj = 0; jj < 16; ++jj) {
      z0 = fmaf(wl[jj], frcp(fexp2(q0[jj] + ka[jj]) + 1.0f), z0);
      z1 = fmaf(wl[jj], frcp(fexp2(q1[jj] + ka[jj]) + 1.0f), z1);
    }
  }
  float* srow = sc + ((size_t)b * SEQN + n0) * SEQM + m;
  srow[0]    = -2.0f * z0;
  srow[SEQM] = -2.0f * z1;
}

// Softmax + PV. grid = NB * (SEQN/8) = 256 blocks, 1024 threads (16 waves).
// Waves 0..7: softmax of one full score row each (512 keys).
// PV: quarter q = t>>8 owns 128 m's; d = t&255; combine quarters via LDS.
__global__ __launch_bounds__(1024) void softpv_kernel(
    const float* __restrict__ sc, const float* __restrict__ value,
    float* __restrict__ out) {
  constexpr int TN = 8;
  __shared__ float sp[TN][SEQM];        // 16 KB: unnormalized p
  __shared__ float pvbuf[3][TN][DV];    // 24 KB: quarter partials
  __shared__ float rs[TN];

  const int t  = threadIdx.x;           // 0..1023
  const int b  = blockIdx.x / (SEQN / TN);
  const int n0 = (blockIdx.x % (SEQN / TN)) * TN;
  const int wave = t >> 6;
  const int lane = t & 63;

  if (wave < TN) {
    const float* __restrict__ srow = sc + ((size_t)b * SEQN + n0 + wave) * SEQM;
    float v[8];
    float mx = -1e30f;
#pragma unroll
    for (int i = 0; i < 8; ++i) {
      v[i] = srow[lane + 64 * i];
      mx = fmaxf(mx, v[i]);
    }
#pragma unroll
    for (int off = 32; off > 0; off >>= 1) mx = fmaxf(mx, __shfl_xor(mx, off));
    float sum = 0.f;
#pragma unroll
    for (int i = 0; i < 8; ++i) {
      const float p = fexp2((v[i] - mx) * kLog2e);
      sum += p;
      sp[wave][lane + 64 * i] = p;
    }
#pragma unroll
    for (int off = 32; off > 0; off >>= 1) sum += __shfl_xor(sum, off);
    if (lane == 0) rs[wave] = 1.0f / sum;
  }
  __syncthreads();

  // PV
  const float* __restrict__ vb = value + (size_t)b * SEQM * DV;
  const int d = t & 255;
  const int q = t >> 8;                 // quarter 0..3
  float o[TN];
#pragma unroll
  for (int n = 0; n < TN; ++n) o[n] = 0.f;
  const int mbeg = q * 128;
  for (int m0 = mbeg; m0 < mbeg + 128; m0 += 4) {
    const float v0 = vb[(size_t)(m0 + 0) * DV + d];
    const float v1 = vb[(size_t)(m0 + 1) * DV + d];
    const float v2 = vb[(size_t)(m0 + 2) * DV + d];
    const float v3 = vb[(size_t)(m0 + 3) * DV + d];
#pragma unroll
    for (int n = 0; n < TN; ++n) {
      const float4 p4 = *reinterpret_cast<const float4*>(&sp[n][m0]);  // broadcast
      o[n] = fmaf(p4.x, v0, fmaf(p4.y, v1, fmaf(p4.z, v2, fmaf(p4.w, v3, o[n]))));
    }
  }
  if (q > 0) {
#pragma unroll
    for (int n = 0; n < TN; ++n) pvbuf[q - 1][n][d] = o[n];
  }
  __syncthreads();
  if (q == 0) {
    const size_t ob = ((size_t)b * SEQN + n0) * DV + (size_t)d;
#pragma unroll
    for (int n = 0; n < TN; ++n) {
      const float r = (o[n] + pvbuf[0][n][d] + pvbuf[1][n][d] + pvbuf[2][n][d]) * rs[n];
      out[ob + (size_t)n * DV] = r;
    }
  }
}

extern "C" void kernel_launch(void* const* d_in, const int* in_sizes, int n_in,
                              void* d_out, int out_size, void* d_ws, size_t ws_size,
                              hipStream_t stream) {
  const float* query = (const float*)d_in[0];   // (4,512,256)
  const float* key   = (const float*)d_in[1];   // (4,512,256)
  const float* value = (const float*)d_in[2];   // (4,512,256)
  const float* W_q   = (const float*)d_in[3];   // (256,128)
  const float* W_k   = (const float*)d_in[4];   // (256,128)
  const float* W_v   = (const float*)d_in[5];   // (128,)
  float* out = (float*)d_out;                   // (4,512,256) f32

  float* qp = (float*)d_ws;                          // 1 MB
  float* kp = qp + (size_t)NB * SEQN * HH;           // 1 MB
  float* sc = kp + (size_t)NB * SEQM * HH;           // 4 MB

  proj_kernel<<<2 * (NB * SEQN) / 8, 256, 0, stream>>>(query, key, W_q, W_k, qp, kp);
  scores_kernel<<<NB * (SEQN / 2) * 2, 256, 0, stream>>>(qp, kp, W_v, sc);
  softpv_kernel<<<NB * (SEQN / 8), 1024, 0, stream>>>(sc, value, out);
}

// Round 4
// 60.771 us; speedup vs baseline: 1.2352x; 1.0638x over previous
//
#include <hip/hip_runtime.h>
#include <math.h>

#define NB   4
#define SEQN 512
#define SEQM 512
#define QS   256   // Q_SIZE == K_SIZE
#define HH   128   // H
#define DV   256   // D_V

// 2*log2(e): pre-scale q,k so exp2(q'+k') == exp(2*(q+k))
static constexpr float kPreScale = 2.8853900817779268f;
static constexpr float kLog2e    = 1.4426950408889634f;

#if __has_builtin(__builtin_amdgcn_exp2f)
__device__ __forceinline__ float fexp2(float x) { return __builtin_amdgcn_exp2f(x); }
#else
__device__ __forceinline__ float fexp2(float x) { return exp2f(x); }
#endif

#if __has_builtin(__builtin_amdgcn_rcpf)
__device__ __forceinline__ float frcp(float x) { return __builtin_amdgcn_rcpf(x); }
#else
__device__ __forceinline__ float frcp(float x) { return 1.0f / x; }
#endif

// Fused q/k projection. grid: 2 * (2048/8) = 512 blocks, 256 threads.
__global__ __launch_bounds__(256) void proj_kernel(
    const float* __restrict__ query, const float* __restrict__ key,
    const float* __restrict__ Wq, const float* __restrict__ Wk,
    float* __restrict__ qp, float* __restrict__ kp) {
  __shared__ float in_lds[8][QS];   // 8 KB
  const int t = threadIdx.x;
  const int half = (NB * SEQN) / 8;            // 256
  const bool isK = blockIdx.x >= half;
  const int rb   = isK ? (blockIdx.x - half) : blockIdx.x;
  const float* __restrict__ in = isK ? key : query;
  const float* __restrict__ W  = isK ? Wk  : Wq;
  float* __restrict__ outp     = isK ? kp  : qp;
  const int row0 = rb * 8;

  const float4* src = reinterpret_cast<const float4*>(in + (size_t)row0 * QS);
  float4* dst = reinterpret_cast<float4*>(&in_lds[0][0]);
  dst[t] = src[t];
  dst[t + 256] = src[t + 256];
  __syncthreads();

  const int j  = t & 127;         // output column
  const int r0 = (t >> 7) * 4;    // 4 rows per thread-half
  float a0 = 0.f, a1 = 0.f, a2 = 0.f, a3 = 0.f;
  for (int k0 = 0; k0 < QS; k0 += 4) {
    const float w0 = W[(k0 + 0) * HH + j];
    const float w1 = W[(k0 + 1) * HH + j];
    const float w2 = W[(k0 + 2) * HH + j];
    const float w3 = W[(k0 + 3) * HH + j];
    const float4 x0 = *reinterpret_cast<const float4*>(&in_lds[r0 + 0][k0]);
    const float4 x1 = *reinterpret_cast<const float4*>(&in_lds[r0 + 1][k0]);
    const float4 x2 = *reinterpret_cast<const float4*>(&in_lds[r0 + 2][k0]);
    const float4 x3 = *reinterpret_cast<const float4*>(&in_lds[r0 + 3][k0]);
    a0 = fmaf(x0.x, w0, fmaf(x0.y, w1, fmaf(x0.z, w2, fmaf(x0.w, w3, a0))));
    a1 = fmaf(x1.x, w0, fmaf(x1.y, w1, fmaf(x1.z, w2, fmaf(x1.w, w3, a1))));
    a2 = fmaf(x2.x, w0, fmaf(x2.y, w1, fmaf(x2.z, w2, fmaf(x2.w, w3, a2))));
    a3 = fmaf(x3.x, w0, fmaf(x3.y, w1, fmaf(x3.z, w2, fmaf(x3.w, w3, a3))));
  }
  outp[(size_t)(row0 + r0 + 0) * HH + j] = a0 * kPreScale;
  outp[(size_t)(row0 + r0 + 1) * HH + j] = a1 * kPreScale;
  outp[(size_t)(row0 + r0 + 2) * HH + j] = a2 * kPreScale;
  outp[(size_t)(row0 + r0 + 3) * HH + j] = a3 * kPreScale;
}

// Scores only. grid = NB * (SEQN/2) * 2 = 2048 blocks, 256 threads, 0 LDS.
// Block: 2 query rows x 256 keys (half). Thread: one key row m.
// Minimal live state: one float4 k-chunk per unroll step, no staging arrays.
__global__ __launch_bounds__(256) void scores_kernel(
    const float* __restrict__ qp, const float* __restrict__ kp,
    const float* __restrict__ wv, float* __restrict__ sc) {
  const int t = threadIdx.x;
  const int bid = blockIdx.x;
  const int mh = bid & 1;
  const int nt = (bid >> 1) & (SEQN / 2 - 1);   // 0..255
  const int b  = bid >> 9;                      // 0..3
  const int n0 = nt * 2;
  const int m  = mh * 256 + t;

  const float* __restrict__ qb = qp + ((size_t)b * SEQN + n0) * HH;  // uniform
  const float* __restrict__ kb = kp + ((size_t)b * SEQM + m) * HH;

  float z0 = 0.f, z1 = 0.f;
#pragma unroll 4
  for (int h = 0; h < HH; h += 4) {
    const float4 f = *reinterpret_cast<const float4*>(kb + h);        // per-lane
    const float4 w = *reinterpret_cast<const float4*>(wv + h);        // uniform -> SGPR
    const float4 a = *reinterpret_cast<const float4*>(qb + h);        // uniform -> SGPR
    const float4 c = *reinterpret_cast<const float4*>(qb + HH + h);   // uniform -> SGPR
    z0 = fmaf(w.x, frcp(fexp2(a.x + f.x) + 1.0f), z0);
    z0 = fmaf(w.y, frcp(fexp2(a.y + f.y) + 1.0f), z0);
    z0 = fmaf(w.z, frcp(fexp2(a.z + f.z) + 1.0f), z0);
    z0 = fmaf(w.w, frcp(fexp2(a.w + f.w) + 1.0f), z0);
    z1 = fmaf(w.x, frcp(fexp2(c.x + f.x) + 1.0f), z1);
    z1 = fmaf(w.y, frcp(fexp2(c.y + f.y) + 1.0f), z1);
    z1 = fmaf(w.z, frcp(fexp2(c.z + f.z) + 1.0f), z1);
    z1 = fmaf(w.w, frcp(fexp2(c.w + f.w) + 1.0f), z1);
  }
  float* srow = sc + ((size_t)b * SEQN + n0) * SEQM + m;
  srow[0]    = -2.0f * z0;
  srow[SEQM] = -2.0f * z1;
}

// Softmax + PV. grid = NB * (SEQN/8) = 256 blocks, 1024 threads (16 waves).
// Waves 0..7: softmax of one full score row each (512 keys).
// PV: thread owns 2 d-columns (d, d+128) and one m-eighth (64 m's);
// each sp float4 broadcast feeds 8 FMAs (4 m x 2 d). LDS combine of 8 partials.
__global__ __launch_bounds__(1024) void softpv_kernel(
    const float* __restrict__ sc, const float* __restrict__ value,
    float* __restrict__ out) {
  constexpr int TN = 8;
  __shared__ float sp[TN][SEQM];          // 16 KB: unnormalized p
  __shared__ float pvbuf[7][TN][DV];      // 56 KB: m-group partials
  __shared__ float rs[TN];

  const int t  = threadIdx.x;             // 0..1023
  const int b  = blockIdx.x / (SEQN / TN);
  const int n0 = (blockIdx.x % (SEQN / TN)) * TN;
  const int wave = t >> 6;
  const int lane = t & 63;

  if (wave < TN) {
    const float* __restrict__ srow = sc + ((size_t)b * SEQN + n0 + wave) * SEQM;
    float v[8];
    float mx = -1e30f;
#pragma unroll
    for (int i = 0; i < 8; ++i) {
      v[i] = srow[lane + 64 * i];
      mx = fmaxf(mx, v[i]);
    }
#pragma unroll
    for (int off = 32; off > 0; off >>= 1) mx = fmaxf(mx, __shfl_xor(mx, off));
    float sum = 0.f;
#pragma unroll
    for (int i = 0; i < 8; ++i) {
      const float p = fexp2((v[i] - mx) * kLog2e);
      sum += p;
      sp[wave][lane + 64 * i] = p;
    }
#pragma unroll
    for (int off = 32; off > 0; off >>= 1) sum += __shfl_xor(sum, off);
    if (lane == 0) rs[wave] = 1.0f / sum;
  }
  __syncthreads();

  // PV
  const float* __restrict__ vb = value + (size_t)b * SEQM * DV;
  const int d  = t & 127;                 // d and d+128
  const int mg = t >> 7;                  // m-eighth 0..7
  float oA[TN], oB[TN];
#pragma unroll
  for (int n = 0; n < TN; ++n) { oA[n] = 0.f; oB[n] = 0.f; }
  const int mbeg = mg * 64;
  for (int m0 = mbeg; m0 < mbeg + 64; m0 += 4) {
    const float vA0 = vb[(size_t)(m0 + 0) * DV + d];
    const float vB0 = vb[(size_t)(m0 + 0) * DV + d + 128];
    const float vA1 = vb[(size_t)(m0 + 1) * DV + d];
    const float vB1 = vb[(size_t)(m0 + 1) * DV + d + 128];
    const float vA2 = vb[(size_t)(m0 + 2) * DV + d];
    const float vB2 = vb[(size_t)(m0 + 2) * DV + d + 128];
    const float vA3 = vb[(size_t)(m0 + 3) * DV + d];
    const float vB3 = vb[(size_t)(m0 + 3) * DV + d + 128];
#pragma unroll
    for (int n = 0; n < TN; ++n) {
      const float4 p4 = *reinterpret_cast<const float4*>(&sp[n][m0]);  // broadcast
      oA[n] = fmaf(p4.x, vA0, fmaf(p4.y, vA1, fmaf(p4.z, vA2, fmaf(p4.w, vA3, oA[n]))));
      oB[n] = fmaf(p4.x, vB0, fmaf(p4.y, vB1, fmaf(p4.z, vB2, fmaf(p4.w, vB3, oB[n]))));
    }
  }
  if (mg > 0) {
#pragma unroll
    for (int n = 0; n < TN; ++n) {
      pvbuf[mg - 1][n][d]       = oA[n];
      pvbuf[mg - 1][n][d + 128] = oB[n];
    }
  }
  __syncthreads();
  if (mg == 0) {
    const size_t ob = ((size_t)b * SEQN + n0) * DV;
#pragma unroll
    for (int n = 0; n < TN; ++n) {
      float accA = oA[n], accB = oB[n];
#pragma unroll
      for (int g = 0; g < 7; ++g) {
        accA += pvbuf[g][n][d];
        accB += pvbuf[g][n][d + 128];
      }
      out[ob + (size_t)n * DV + d]       = accA * rs[n];
      out[ob + (size_t)n * DV + d + 128] = accB * rs[n];
    }
  }
}

extern "C" void kernel_launch(void* const* d_in, const int* in_sizes, int n_in,
                              void* d_out, int out_size, void* d_ws, size_t ws_size,
                              hipStream_t stream) {
  const float* query = (const float*)d_in[0];   // (4,512,256)
  const float* key   = (const float*)d_in[1];   // (4,512,256)
  const float* value = (const float*)d_in[2];   // (4,512,256)
  const float* W_q   = (const float*)d_in[3];   // (256,128)
  const float* W_k   = (const float*)d_in[4];   // (256,128)
  const float* W_v   = (const float*)d_in[5];   // (128,)
  float* out = (float*)d_out;                   // (4,512,256) f32

  float* qp = (float*)d_ws;                          // 1 MB
  float* kp = qp + (size_t)NB * SEQN * HH;           // 1 MB
  float* sc = kp + (size_t)NB * SEQM * HH;           // 4 MB

  proj_kernel<<<2 * (NB * SEQN) / 8, 256, 0, stream>>>(query, key, W_q, W_k, qp, kp);
  scores_kernel<<<NB * (SEQN / 2) * 2, 256, 0, stream>>>(qp, kp, W_v, sc);
  softpv_kernel<<<NB * (SEQN / 8), 1024, 0, stream>>>(sc, value, out);
}

// Round 6
// 53.641 us; speedup vs baseline: 1.3994x; 1.1329x over previous
//
#include <hip/hip_runtime.h>
#include <math.h>

#define NB   4
#define SEQN 512
#define SEQM 512
#define QS   256   // Q_SIZE == K_SIZE
#define HH   128   // H
#define DV   256   // D_V

static constexpr float kPreScale = 2.8853900817779268f;  // 2*log2(e)
static constexpr float kLog2e    = 1.4426950408889634f;

#if __has_builtin(__builtin_amdgcn_exp2f)
__device__ __forceinline__ float fexp2(float x) { return __builtin_amdgcn_exp2f(x); }
#else
__device__ __forceinline__ float fexp2(float x) { return exp2f(x); }
#endif

#if __has_builtin(__builtin_amdgcn_rcpf)
__device__ __forceinline__ float frcp(float x) { return __builtin_amdgcn_rcpf(x); }
#else
__device__ __forceinline__ float frcp(float x) { return 1.0f / x; }
#endif

// Fused q/k projection + tanh precompute.
// grid: 2 * (2048/8) = 512 blocks, 256 threads. Block: 8 rows x 128 cols.
// Output row layout (256 floats): [ A_h = tanh(proj_h) | A''_h = wv_h * A_h ]
__global__ __launch_bounds__(256) void proj_kernel(
    const float* __restrict__ query, const float* __restrict__ key,
    const float* __restrict__ Wq, const float* __restrict__ Wk,
    const float* __restrict__ wv,
    float* __restrict__ qt, float* __restrict__ kt) {
  __shared__ float in_lds[8][QS];   // 8 KB
  const int t = threadIdx.x;
  const int half = (NB * SEQN) / 8;            // 256
  const bool isK = blockIdx.x >= half;
  const int rb   = isK ? (blockIdx.x - half) : blockIdx.x;
  const float* __restrict__ in = isK ? key : query;
  const float* __restrict__ W  = isK ? Wk  : Wq;
  float* __restrict__ outp     = isK ? kt  : qt;
  const int row0 = rb * 8;

  const float4* src = reinterpret_cast<const float4*>(in + (size_t)row0 * QS);
  float4* dst = reinterpret_cast<float4*>(&in_lds[0][0]);
  dst[t] = src[t];
  dst[t + 256] = src[t + 256];
  __syncthreads();

  const int j  = t & 127;         // output column (h)
  const int r0 = (t >> 7) * 4;    // 4 rows per thread-half
  float a0 = 0.f, a1 = 0.f, a2 = 0.f, a3 = 0.f;
  for (int k0 = 0; k0 < QS; k0 += 4) {
    const float w0 = W[(k0 + 0) * HH + j];
    const float w1 = W[(k0 + 1) * HH + j];
    const float w2 = W[(k0 + 2) * HH + j];
    const float w3 = W[(k0 + 3) * HH + j];
    const float4 x0 = *reinterpret_cast<const float4*>(&in_lds[r0 + 0][k0]);
    const float4 x1 = *reinterpret_cast<const float4*>(&in_lds[r0 + 1][k0]);
    const float4 x2 = *reinterpret_cast<const float4*>(&in_lds[r0 + 2][k0]);
    const float4 x3 = *reinterpret_cast<const float4*>(&in_lds[r0 + 3][k0]);
    a0 = fmaf(x0.x, w0, fmaf(x0.y, w1, fmaf(x0.z, w2, fmaf(x0.w, w3, a0))));
    a1 = fmaf(x1.x, w0, fmaf(x1.y, w1, fmaf(x1.z, w2, fmaf(x1.w, w3, a1))));
    a2 = fmaf(x2.x, w0, fmaf(x2.y, w1, fmaf(x2.z, w2, fmaf(x2.w, w3, a2))));
    a3 = fmaf(x3.x, w0, fmaf(x3.y, w1, fmaf(x3.z, w2, fmaf(x3.w, w3, a3))));
  }
  const float wvj = wv[j];
  float acc[4] = {a0, a1, a2, a3};
#pragma unroll
  for (int r = 0; r < 4; ++r) {
    const float e  = fexp2(acc[r] * kPreScale);          // e^{2x}
    const float rc = frcp(e + 1.0f);
    float A = fmaf(-2.0f, rc, 1.0f);                     // tanh(x)
    A = fminf(fmaxf(A, -0.99999988f), 0.99999988f);      // keep d = 1+AB > 0
    const size_t rowoff = (size_t)(row0 + r0 + r) * (2 * HH);
    outp[rowoff + j]      = A;
    outp[rowoff + HH + j] = wvj * A;
  }
}

// Scores via tanh addition identity + product tree: NO transcendentals per
// (n,m,h) element; one rcp per score.
// score[b][n][m] = sum_h wv_h * (A+B)/(1+AB)   with A''+B'' = wv*(A+B)
// grid = NB * (SEQN/8) * 2 = 512 blocks, 256 threads. Thread: 8 scores (1 m, 8 n).
__global__ __launch_bounds__(256) void scores_kernel(
    const float* __restrict__ qt, const float* __restrict__ kt,
    float* __restrict__ sc) {
  const int t   = threadIdx.x;
  const int bid = blockIdx.x;
  const int mh  = bid & 1;
  const int nb  = (bid >> 1) & 63;
  const int b   = bid >> 7;
  const int n0  = nb * 8;
  const int m   = mh * 256 + t;

  const float* __restrict__ qrow = qt + ((size_t)b * SEQN + n0) * (2 * HH);  // uniform
  const float* __restrict__ krow = kt + ((size_t)b * SEQM + m) * (2 * HH);   // per-lane

  float N[8], D[8];
#pragma unroll
  for (int n = 0; n < 8; ++n) { N[n] = 0.f; D[n] = 1.f; }

  for (int h0 = 0; h0 < HH; h0 += 8) {
    const float4 b0 = *reinterpret_cast<const float4*>(krow + h0);
    const float4 b1 = *reinterpret_cast<const float4*>(krow + h0 + 4);
    const float4 u0 = *reinterpret_cast<const float4*>(krow + HH + h0);
    const float4 u1 = *reinterpret_cast<const float4*>(krow + HH + h0 + 4);
#pragma unroll
    for (int n = 0; n < 8; ++n) {
      const float* qr = qrow + (size_t)n * (2 * HH);
      const float4 a0 = *reinterpret_cast<const float4*>(qr + h0);           // uniform
      const float4 a1 = *reinterpret_cast<const float4*>(qr + h0 + 4);       // uniform
      const float4 v0 = *reinterpret_cast<const float4*>(qr + HH + h0);      // uniform
      const float4 v1 = *reinterpret_cast<const float4*>(qr + HH + h0 + 4);  // uniform
      // s_i = A''+B'', d_i = 1 + A*B  (d in (0,2))
      const float s0 = v0.x + u0.x, d0 = fmaf(a0.x, b0.x, 1.0f);
      const float s1 = v0.y + u0.y, d1 = fmaf(a0.y, b0.y, 1.0f);
      const float s2 = v0.z + u0.z, d2 = fmaf(a0.z, b0.z, 1.0f);
      const float s3 = v0.w + u0.w, d3 = fmaf(a0.w, b0.w, 1.0f);
      const float s4 = v1.x + u1.x, d4 = fmaf(a1.x, b1.x, 1.0f);
      const float s5 = v1.y + u1.y, d5 = fmaf(a1.y, b1.y, 1.0f);
      const float s6 = v1.z + u1.z, d6 = fmaf(a1.z, b1.z, 1.0f);
      const float s7 = v1.w + u1.w, d7 = fmaf(a1.w, b1.w, 1.0f);
      // pairwise rational tree: sum s_i/d_i -> t07/e07
      const float t01 = fmaf(s0, d1, s1 * d0), e01 = d0 * d1;
      const float t23 = fmaf(s2, d3, s3 * d2), e23 = d2 * d3;
      const float t45 = fmaf(s4, d5, s5 * d4), e45 = d4 * d5;
      const float t67 = fmaf(s6, d7, s7 * d6), e67 = d6 * d7;
      const float t03 = fmaf(t01, e23, t23 * e01), e03 = e01 * e23;
      const float t47 = fmaf(t45, e67, t67 * e45), e47 = e45 * e67;
      const float t07 = fmaf(t03, e47, t47 * e03), e07 = e03 * e47;
      // fold into running rational accumulator
      N[n] = fmaf(N[n], e07, t07 * D[n]);
      D[n] *= e07;
    }
  }
  float* srow = sc + ((size_t)b * SEQN + n0) * SEQM + m;
#pragma unroll
  for (int n = 0; n < 8; ++n)
    srow[(size_t)n * SEQM] = N[n] * frcp(D[n]);   // score = N/D (no extra scale!)
}

// Softmax + PV. grid = NB * (SEQN/8) = 256 blocks, 512 threads (8 waves).
// Waves 0..7: softmax of one full score row (512 keys).
// PV: thread owns 4 d-cols (dg+64k) and one m-eighth (64 m's); every sp
// broadcast read feeds 16 FMAs. All 8 m-groups write pvbuf; all combine.
__global__ __launch_bounds__(512) void softpv_kernel(
    const float* __restrict__ sc, const float* __restrict__ value,
    float* __restrict__ out) {
  __shared__ float sp[8][SEQM];        // 16 KB: unnormalized p
  __shared__ float pvbuf[8][8][DV];    // 64 KB: m-group partials
  __shared__ float rs[8];

  const int t    = threadIdx.x;        // 0..511
  const int b    = blockIdx.x >> 6;
  const int n0   = (blockIdx.x & 63) * 8;
  const int wave = t >> 6;
  const int lane = t & 63;

  {
    const float* __restrict__ srow = sc + ((size_t)b * SEQN + n0 + wave) * SEQM;
    float v[8];
    float mx = -1e30f;
#pragma unroll
    for (int i = 0; i < 8; ++i) {
      v[i] = srow[lane + 64 * i];
      mx = fmaxf(mx, v[i]);
    }
#pragma unroll
    for (int off = 32; off > 0; off >>= 1) mx = fmaxf(mx, __shfl_xor(mx, off));
    float sum = 0.f;
#pragma unroll
    for (int i = 0; i < 8; ++i) {
      const float p = fexp2((v[i] - mx) * kLog2e);
      sum += p;
      sp[wave][lane + 64 * i] = p;
    }
#pragma unroll
    for (int off = 32; off > 0; off >>= 1) sum += __shfl_xor(sum, off);
    if (lane == 0) rs[wave] = 1.0f / sum;
  }
  __syncthreads();

  // PV partials: mg = m-eighth, dg = d base
  const float* __restrict__ vb = value + (size_t)b * SEQM * DV;
  const int dg = t & 63;
  const int mg = t >> 6;
  float oA[8], oB[8], oC[8], oD[8];
#pragma unroll
  for (int n = 0; n < 8; ++n) { oA[n] = 0.f; oB[n] = 0.f; oC[n] = 0.f; oD[n] = 0.f; }
  const int mbeg = mg * 64;
  for (int m0 = mbeg; m0 < mbeg + 64; m0 += 4) {
    float vA[4], vB[4], vC[4], vD[4];
#pragma unroll
    for (int mm = 0; mm < 4; ++mm) {
      const float* vr = vb + (size_t)(m0 + mm) * DV + dg;
      vA[mm] = vr[0];
      vB[mm] = vr[64];
      vC[mm] = vr[128];
      vD[mm] = vr[192];
    }
#pragma unroll
    for (int n = 0; n < 8; ++n) {
      const float4 p4 = *reinterpret_cast<const float4*>(&sp[n][m0]);  // broadcast
      oA[n] = fmaf(p4.x, vA[0], fmaf(p4.y, vA[1], fmaf(p4.z, vA[2], fmaf(p4.w, vA[3], oA[n]))));
      oB[n] = fmaf(p4.x, vB[0], fmaf(p4.y, vB[1], fmaf(p4.z, vB[2], fmaf(p4.w, vB[3], oB[n]))));
      oC[n] = fmaf(p4.x, vC[0], fmaf(p4.y, vC[1], fmaf(p4.z, vC[2], fmaf(p4.w, vC[3], oC[n]))));
      oD[n] = fmaf(p4.x, vD[0], fmaf(p4.y, vD[1], fmaf(p4.z, vD[2], fmaf(p4.w, vD[3], oD[n]))));
    }
  }
#pragma unroll
  for (int n = 0; n < 8; ++n) {
    pvbuf[mg][n][dg]       = oA[n];
    pvbuf[mg][n][dg + 64]  = oB[n];
    pvbuf[mg][n][dg + 128] = oC[n];
    pvbuf[mg][n][dg + 192] = oD[n];
  }
  __syncthreads();

  // combine: wave = n, lane = dg; 4 d's per thread
  {
    const int n = wave;
    const float r = rs[n];
    const size_t ob = ((size_t)b * SEQN + n0 + n) * DV;
#pragma unroll
    for (int k = 0; k < 4; ++k) {
      const int d = lane + 64 * k;
      float acc = 0.f;
#pragma unroll
      for (int g = 0; g < 8; ++g) acc += pvbuf[g][n][d];
      out[ob + d] = acc * r;
    }
  }
}

extern "C" void kernel_launch(void* const* d_in, const int* in_sizes, int n_in,
                              void* d_out, int out_size, void* d_ws, size_t ws_size,
                              hipStream_t stream) {
  const float* query = (const float*)d_in[0];   // (4,512,256)
  const float* key   = (const float*)d_in[1];   // (4,512,256)
  const float* value = (const float*)d_in[2];   // (4,512,256)
  const float* W_q   = (const float*)d_in[3];   // (256,128)
  const float* W_k   = (const float*)d_in[4];   // (256,128)
  const float* W_v   = (const float*)d_in[5];   // (128,)
  float* out = (float*)d_out;                   // (4,512,256) f32

  // qt parks in d_out (2 MB, fully overwritten by softpv at the end);
  // kt + sc live in ws (2 MB + 4 MB = 6 MB).
  float* qt = (float*)d_out;                          // (2048, 256)
  float* kt = (float*)d_ws;                           // (2048, 256)
  float* sc = kt + (size_t)NB * SEQM * (2 * HH);      // (4,512,512)

  proj_kernel<<<2 * (NB * SEQN) / 8, 256, 0, stream>>>(query, key, W_q, W_k, W_v, qt, kt);
  scores_kernel<<<NB * (SEQN / 8) * 2, 256, 0, stream>>>(qt, kt, sc);
  softpv_kernel<<<NB * (SEQN / 8), 512, 0, stream>>>(sc, value, out);
}

// Round 7
// 52.633 us; speedup vs baseline: 1.4262x; 1.0192x over previous
//
#include <hip/hip_runtime.h>
#include <math.h>

#define NB   4
#define SEQN 512
#define SEQM 512
#define QS   256   // Q_SIZE == K_SIZE
#define HH   128   // H
#define DV   256   // D_V
#define BM   (NB * SEQM)   // 2048 global k rows

static constexpr float kPreScale = 2.8853900817779268f;  // 2*log2(e)
static constexpr float kLog2e    = 1.4426950408889634f;

#if __has_builtin(__builtin_amdgcn_exp2f)
__device__ __forceinline__ float fexp2(float x) { return __builtin_amdgcn_exp2f(x); }
#else
__device__ __forceinline__ float fexp2(float x) { return exp2f(x); }
#endif

#if __has_builtin(__builtin_amdgcn_rcpf)
__device__ __forceinline__ float frcp(float x) { return __builtin_amdgcn_rcpf(x); }
#else
__device__ __forceinline__ float frcp(float x) { return 1.0f / x; }
#endif

// Fused q/k projection + tanh precompute.
// grid: 2 * 256 = 512 blocks, 256 threads. Block: 8 rows x 128 cols.
// Q output (row-major): qt[row][ A_0..A_127 | wv_0*A_0 .. wv_127*A_127 ]
// K output (transposed, packed): kt[h][global_row] = float2(A, wv_h*A)
__global__ __launch_bounds__(256) void proj_kernel(
    const float* __restrict__ query, const float* __restrict__ key,
    const float* __restrict__ Wq, const float* __restrict__ Wk,
    const float* __restrict__ wv,
    float* __restrict__ qt, float2* __restrict__ kt) {
  const int t = threadIdx.x;
  const int half = (NB * SEQN) / 8;            // 256
  const bool isK = blockIdx.x >= half;
  const int rb   = isK ? (blockIdx.x - half) : blockIdx.x;
  const float* __restrict__ in = isK ? key : query;
  const float* __restrict__ W  = isK ? Wk  : Wq;
  const int row0 = rb * 8;

  const int j  = t & 127;                                      // output column (h)
  const int r0 = __builtin_amdgcn_readfirstlane((t >> 7) * 4); // wave-uniform -> SGPR

  // wave-uniform input rows -> scalar loads (no LDS staging needed)
  const float* __restrict__ x0p = in + (size_t)(row0 + r0 + 0) * QS;
  const float* __restrict__ x1p = in + (size_t)(row0 + r0 + 1) * QS;
  const float* __restrict__ x2p = in + (size_t)(row0 + r0 + 2) * QS;
  const float* __restrict__ x3p = in + (size_t)(row0 + r0 + 3) * QS;

  float a0 = 0.f, a1 = 0.f, a2 = 0.f, a3 = 0.f;
  for (int k0 = 0; k0 < QS; k0 += 4) {
    const float w0 = W[(k0 + 0) * HH + j];
    const float w1 = W[(k0 + 1) * HH + j];
    const float w2 = W[(k0 + 2) * HH + j];
    const float w3 = W[(k0 + 3) * HH + j];
    const float4 x0 = *reinterpret_cast<const float4*>(x0p + k0);  // s_load
    const float4 x1 = *reinterpret_cast<const float4*>(x1p + k0);
    const float4 x2 = *reinterpret_cast<const float4*>(x2p + k0);
    const float4 x3 = *reinterpret_cast<const float4*>(x3p + k0);
    a0 = fmaf(x0.x, w0, fmaf(x0.y, w1, fmaf(x0.z, w2, fmaf(x0.w, w3, a0))));
    a1 = fmaf(x1.x, w0, fmaf(x1.y, w1, fmaf(x1.z, w2, fmaf(x1.w, w3, a1))));
    a2 = fmaf(x2.x, w0, fmaf(x2.y, w1, fmaf(x2.z, w2, fmaf(x2.w, w3, a2))));
    a3 = fmaf(x3.x, w0, fmaf(x3.y, w1, fmaf(x3.z, w2, fmaf(x3.w, w3, a3))));
  }
  const float wvj = wv[j];
  float acc[4] = {a0, a1, a2, a3};
#pragma unroll
  for (int r = 0; r < 4; ++r) {
    const float e  = fexp2(acc[r] * kPreScale);          // e^{2x}
    const float rc = frcp(e + 1.0f);
    float A = fmaf(-2.0f, rc, 1.0f);                     // tanh(x)
    A = fminf(fmaxf(A, -0.99999988f), 0.99999988f);      // keep d = 1+AB > 0
    const int grow = row0 + r0 + r;
    if (isK) {
      kt[(size_t)j * BM + grow] = make_float2(A, wvj * A);
    } else {
      qt[(size_t)grow * (2 * HH) + j]      = A;
      qt[(size_t)grow * (2 * HH) + HH + j] = wvj * A;
    }
  }
}

// Fused scores + softmax + PV.
// grid = NB * (SEQN/4) = 512 blocks, 512 threads (8 waves), 40 KB LDS.
// Phase 1: thread t = key col m; 4 query rows; tanh-identity rational tree
//          (zero transcendentals); k reads coalesced via [h][m] layout.
// Phase 2: softmax, 2 waves per row.
// Phase 3: PV, thread owns d-quad 4*(t&63) and m-eighth t>>6; LDS combine.
__global__ __launch_bounds__(512) void fused_kernel(
    const float* __restrict__ qt, const float2* __restrict__ kt,
    const float* __restrict__ value, float* __restrict__ out) {
  __shared__ float sp[4][SEQM];          // 8 KB: scores then unnormalized p
  __shared__ float pvbuf[8][4][DV];      // 32 KB: m-group partials
  __shared__ float wred[16];             // wmax[0..7], wsum[8..15]

  const int t  = threadIdx.x;            // 0..511
  const int b  = blockIdx.x >> 7;
  const int n0 = (blockIdx.x & 127) * 4;
  const int m  = t;

  const float* __restrict__ qb = qt + ((size_t)b * SEQN + n0) * (2 * HH);  // uniform
  const float2* __restrict__ kb = kt + (size_t)b * SEQM + m;               // coalesced

  float N[4], D[4];
#pragma unroll
  for (int n = 0; n < 4; ++n) { N[n] = 0.f; D[n] = 1.f; }

  for (int h0 = 0; h0 < HH; h0 += 8) {
    float kA[8], kW[8];
#pragma unroll
    for (int jj = 0; jj < 8; ++jj) {
      const float2 f = kb[(size_t)(h0 + jj) * BM];   // 512B/wave, coalesced
      kA[jj] = f.x; kW[jj] = f.y;
    }
#pragma unroll
    for (int n = 0; n < 4; ++n) {
      const float* qr = qb + n * (2 * HH);
      const float4 a0 = *reinterpret_cast<const float4*>(qr + h0);           // s_load
      const float4 a1 = *reinterpret_cast<const float4*>(qr + h0 + 4);
      const float4 v0 = *reinterpret_cast<const float4*>(qr + HH + h0);
      const float4 v1 = *reinterpret_cast<const float4*>(qr + HH + h0 + 4);
      // s_i = wv*(A+B), d_i = 1 + A*B  (d in (0,2))
      const float s0 = v0.x + kW[0], d0 = fmaf(a0.x, kA[0], 1.0f);
      const float s1 = v0.y + kW[1], d1 = fmaf(a0.y, kA[1], 1.0f);
      const float s2 = v0.z + kW[2], d2 = fmaf(a0.z, kA[2], 1.0f);
      const float s3 = v0.w + kW[3], d3 = fmaf(a0.w, kA[3], 1.0f);
      const float s4 = v1.x + kW[4], d4 = fmaf(a1.x, kA[4], 1.0f);
      const float s5 = v1.y + kW[5], d5 = fmaf(a1.y, kA[5], 1.0f);
      const float s6 = v1.z + kW[6], d6 = fmaf(a1.z, kA[6], 1.0f);
      const float s7 = v1.w + kW[7], d7 = fmaf(a1.w, kA[7], 1.0f);
      // pairwise rational tree: sum s_i/d_i -> t07/e07
      const float t01 = fmaf(s0, d1, s1 * d0), e01 = d0 * d1;
      const float t23 = fmaf(s2, d3, s3 * d2), e23 = d2 * d3;
      const float t45 = fmaf(s4, d5, s5 * d4), e45 = d4 * d5;
      const float t67 = fmaf(s6, d7, s7 * d6), e67 = d6 * d7;
      const float t03 = fmaf(t01, e23, t23 * e01), e03 = e01 * e23;
      const float t47 = fmaf(t45, e67, t67 * e45), e47 = e45 * e67;
      const float t07 = fmaf(t03, e47, t47 * e03), e07 = e03 * e47;
      N[n] = fmaf(N[n], e07, t07 * D[n]);
      D[n] *= e07;
    }
  }
#pragma unroll
  for (int n = 0; n < 4; ++n) sp[n][m] = N[n] * frcp(D[n]);
  __syncthreads();

  // softmax over m: 8 waves, 4 rows -> 2 waves per row (256 elems each)
  const int wave = t >> 6;
  const int lane = t & 63;
  const int row  = wave & 3;
  const int hv   = wave >> 2;
  float v[4];
  float mx = -1e30f;
#pragma unroll
  for (int i = 0; i < 4; ++i) {
    v[i] = sp[row][hv * 256 + lane + 64 * i];
    mx = fmaxf(mx, v[i]);
  }
#pragma unroll
  for (int off = 32; off > 0; off >>= 1) mx = fmaxf(mx, __shfl_xor(mx, off));
  if (lane == 0) wred[wave] = mx;
  __syncthreads();
  mx = fmaxf(wred[row], wred[row + 4]);
  float sum = 0.f;
#pragma unroll
  for (int i = 0; i < 4; ++i) {
    const float p = fexp2((v[i] - mx) * kLog2e);
    sum += p;
    sp[row][hv * 256 + lane + 64 * i] = p;   // unnormalized
  }
#pragma unroll
  for (int off = 32; off > 0; off >>= 1) sum += __shfl_xor(sum, off);
  if (lane == 0) wred[8 + wave] = sum;
  __syncthreads();

  // PV: dq = d-quad base, mg = m-eighth (64 m's)
  const float* __restrict__ vb = value + (size_t)b * SEQM * DV;
  const int dq = (t & 63) * 4;
  const int mg = t >> 6;
  float o[4][4];
#pragma unroll
  for (int n = 0; n < 4; ++n)
#pragma unroll
    for (int jj = 0; jj < 4; ++jj) o[n][jj] = 0.f;
  const int mbeg = mg * 64;
  for (int mi = 0; mi < 64; mi += 4) {
    const int m0 = mbeg + mi;
    const float4 vv0 = *reinterpret_cast<const float4*>(vb + (size_t)(m0 + 0) * DV + dq);
    const float4 vv1 = *reinterpret_cast<const float4*>(vb + (size_t)(m0 + 1) * DV + dq);
    const float4 vv2 = *reinterpret_cast<const float4*>(vb + (size_t)(m0 + 2) * DV + dq);
    const float4 vv3 = *reinterpret_cast<const float4*>(vb + (size_t)(m0 + 3) * DV + dq);
#pragma unroll
    for (int n = 0; n < 4; ++n) {
      const float4 p4 = *reinterpret_cast<const float4*>(&sp[n][m0]);  // broadcast
      o[n][0] = fmaf(p4.x, vv0.x, fmaf(p4.y, vv1.x, fmaf(p4.z, vv2.x, fmaf(p4.w, vv3.x, o[n][0]))));
      o[n][1] = fmaf(p4.x, vv0.y, fmaf(p4.y, vv1.y, fmaf(p4.z, vv2.y, fmaf(p4.w, vv3.y, o[n][1]))));
      o[n][2] = fmaf(p4.x, vv0.z, fmaf(p4.y, vv1.z, fmaf(p4.z, vv2.z, fmaf(p4.w, vv3.z, o[n][2]))));
      o[n][3] = fmaf(p4.x, vv0.w, fmaf(p4.y, vv1.w, fmaf(p4.z, vv2.w, fmaf(p4.w, vv3.w, o[n][3]))));
    }
  }
#pragma unroll
  for (int n = 0; n < 4; ++n)
    *reinterpret_cast<float4*>(&pvbuf[mg][n][dq]) =
        make_float4(o[n][0], o[n][1], o[n][2], o[n][3]);
  __syncthreads();

  // combine: wave -> (row cn, d-half); 2 d's per thread
  {
    const int cn    = wave & 3;
    const int dbase = (wave >> 2) * 128;
    const float rsn = frcp(wred[8 + cn] + wred[8 + cn + 4]);
    const size_t ob = ((size_t)b * SEQN + n0 + cn) * DV;
#pragma unroll
    for (int k2 = 0; k2 < 2; ++k2) {
      const int d = dbase + k2 * 64 + lane;
      float acc = 0.f;
#pragma unroll
      for (int g = 0; g < 8; ++g) acc += pvbuf[g][cn][d];
      out[ob + d] = acc * rsn;
    }
  }
}

extern "C" void kernel_launch(void* const* d_in, const int* in_sizes, int n_in,
                              void* d_out, int out_size, void* d_ws, size_t ws_size,
                              hipStream_t stream) {
  const float* query = (const float*)d_in[0];   // (4,512,256)
  const float* key   = (const float*)d_in[1];   // (4,512,256)
  const float* value = (const float*)d_in[2];   // (4,512,256)
  const float* W_q   = (const float*)d_in[3];   // (256,128)
  const float* W_k   = (const float*)d_in[4];   // (256,128)
  const float* W_v   = (const float*)d_in[5];   // (128,)
  float* out = (float*)d_out;                   // (4,512,256) f32

  // qt parks in d_out (2 MB): fused block (b,n0) reads only its OWN 4 q-rows
  // in phase 1 and overwrites exactly those rows in phase 3 -> no hazard.
  float*  qt = (float*)d_out;                   // (2048, 256) [A | wv*A]
  float2* kt = (float2*)d_ws;                   // (128, 2048) float2(A, wv*A), 2 MB

  proj_kernel<<<2 * (NB * SEQN) / 8, 256, 0, stream>>>(query, key, W_q, W_k, W_v, qt, kt);
  fused_kernel<<<NB * (SEQN / 4), 512, 0, stream>>>(qt, kt, value, out);
}